// Round 9
// baseline (180.404 us; speedup 1.0000x reference)
//
#include <hip/hip_runtime.h>

#define AS1 __attribute__((address_space(1)))
#define AS3 __attribute__((address_space(3)))
#define CHUNK 256
#define PREP_GRID 2048

__device__ __forceinline__ void gld_lds16(const float* g, float* l) {
  __builtin_amdgcn_global_load_lds((const AS1 void*)g, (AS3 void*)l, 16, 0, 0);
}

#define WAITVM0  do { asm volatile("s_waitcnt vmcnt(0)" ::: "memory"); __builtin_amdgcn_sched_barrier(0); } while (0)
#define WAITLGKM do { asm volatile("s_waitcnt lgkmcnt(0)" ::: "memory"); __builtin_amdgcn_sched_barrier(0); } while (0)
#define BAR __builtin_amdgcn_s_barrier()

// Streams r + ri once. Outputs: zb (u8 argmax), wpair (float2 gated resp),
// pigp (per-block partial ri column sums -> reduced later; no atomics).
__global__ __launch_bounds__(256) void prep_k(
    const float* __restrict__ r, const float* __restrict__ ri,
    unsigned char* __restrict__ zb, float* __restrict__ wpairf,
    float* __restrict__ pigp, int n)
{
  __shared__ float lpi[256][33];
  float acc[32];
#pragma unroll
  for (int c = 0; c < 32; ++c) acc[c] = 0.f;

  for (int i = blockIdx.x * blockDim.x + threadIdx.x; i < n;
       i += gridDim.x * blockDim.x) {
    const float4* rr = (const float4*)(r + (size_t)i * 16);
    float4 a0 = rr[0], a1 = rr[1], a2 = rr[2], a3 = rr[3];
    float best = a0.x; int z = 0;
#define CHK(v, c) if ((v) > best) { best = (v); z = (c); }
    CHK(a0.y,1) CHK(a0.z,2) CHK(a0.w,3)
    CHK(a1.x,4) CHK(a1.y,5) CHK(a1.z,6) CHK(a1.w,7)
    CHK(a2.x,8) CHK(a2.y,9) CHK(a2.z,10) CHK(a2.w,11)
    CHK(a3.x,12) CHK(a3.y,13) CHK(a3.z,14) CHK(a3.w,15)
#undef CHK
    const float4* qq = (const float4*)(ri + (size_t)i * 32);
    float4 v0 = qq[0], v1 = qq[1], v2 = qq[2], v3 = qq[3];
    float4 v4 = qq[4], v5 = qq[5], v6 = qq[6], v7 = qq[7];
    acc[0]+=v0.x; acc[1]+=v0.y; acc[2]+=v0.z; acc[3]+=v0.w;
    acc[4]+=v1.x; acc[5]+=v1.y; acc[6]+=v1.z; acc[7]+=v1.w;
    acc[8]+=v2.x; acc[9]+=v2.y; acc[10]+=v2.z; acc[11]+=v2.w;
    acc[12]+=v3.x; acc[13]+=v3.y; acc[14]+=v3.z; acc[15]+=v3.w;
    acc[16]+=v4.x; acc[17]+=v4.y; acc[18]+=v4.z; acc[19]+=v4.w;
    acc[20]+=v5.x; acc[21]+=v5.y; acc[22]+=v5.z; acc[23]+=v5.w;
    acc[24]+=v6.x; acc[25]+=v6.y; acc[26]+=v6.z; acc[27]+=v6.w;
    acc[28]+=v7.x; acc[29]+=v7.y; acc[30]+=v7.z; acc[31]+=v7.w;
    int q = z >> 1;
    float4 sel = q < 4 ? (q < 2 ? (q == 0 ? v0 : v1) : (q == 2 ? v2 : v3))
                       : (q < 6 ? (q == 4 ? v4 : v5) : (q == 6 ? v6 : v7));
    float w0 = (z & 1) ? sel.z : sel.x;
    float w1 = (z & 1) ? sel.w : sel.y;
    zb[i] = (unsigned char)z;
    *(float2*)&wpairf[(size_t)i * 2] = make_float2(w0, w1);
  }

#pragma unroll
  for (int c = 0; c < 32; ++c) lpi[threadIdx.x][c] = acc[c];
  __syncthreads();
  if (threadIdx.x < 32) {
    float s = 0.f;
    for (int q = 0; q < 256; ++q) s += lpi[q][threadIdx.x];
    pigp[blockIdx.x * 32 + threadIdx.x] = s;  // per-block partial, no atomic
  }
}

// ---- named-scalar accumulator groups (no arrays -> no scratch) ----
#define DECL_GRP(P) \
  float4 P##r0 = make_float4(0,0,0,0), P##r1 = make_float4(0,0,0,0), \
         P##r2 = make_float4(0,0,0,0), P##r3 = make_float4(0,0,0,0), \
         P##m  = make_float4(0,0,0,0); \
  float P##d = 0.f;

#define FMA4(ACC, S, V) \
  ACC.x += (S) * (V).x; ACC.y += (S) * (V).y; \
  ACC.z += (S) * (V).z; ACC.w += (S) * (V).w;

#define UPD_GRP(P, W, X1, X2) { float s_; \
  s_ = (W) * (X1).x; FMA4(P##r0, s_, X2); \
  s_ = (W) * (X1).y; FMA4(P##r1, s_, X2); \
  s_ = (W) * (X1).z; FMA4(P##r2, s_, X2); \
  s_ = (W) * (X1).w; FMA4(P##r3, s_, X2); \
  FMA4(P##m, W, X2); \
  P##d += (W); }

#define CLUSTER_LOOP(KK, A, B, LP) { \
  const int cnt_ = lcnt[LP][KK]; \
  const unsigned char* lk_ = &list[LP][KK][0]; \
  _Pragma("unroll 2") \
  for (int j = 0; j < cnt_; ++j) { \
    int p_ = lk_[j]; \
    float2 wp_ = *(const float2*)&wb[p_ * 2]; \
    float4 x1_ = *(const float4*)&xbuf[p_ * 32 + g1 * 4]; \
    float4 x2_ = *(const float4*)&xbuf[p_ * 32 + g2 * 4]; \
    UPD_GRP(A, wp_.x, x1_, x2_); \
    UPD_GRP(B, wp_.y, x1_, x2_); \
  } }

// Plain cached float4 stores to this block's partial slice (no global atomics:
// R3-R6 showed scattered fp32 atomicAdd = 64B uncached line traffic per touch).
#define STORE_GRP(P, COMP) { \
  float* dst_ = m2p + ((size_t)blockIdx.x * 32 + (COMP)) * 1024; \
  *(float4*)&dst_[(g1 * 4 + 0) * 32 + g2 * 4] = P##r0; \
  *(float4*)&dst_[(g1 * 4 + 1) * 32 + g2 * 4] = P##r1; \
  *(float4*)&dst_[(g1 * 4 + 2) * 32 + g2 * 4] = P##r2; \
  *(float4*)&dst_[(g1 * 4 + 3) * 32 + g2 * 4] = P##r3; \
  if (g1 == 0) \
    *(float4*)&musp[((size_t)blockIdx.x * 32 + (COMP)) * 32 + g2 * 4] = P##m; \
  if (l == 0) dnp[blockIdx.x * 32 + (COMP)] = P##d; }

// X double-buffered via global_load_lds; w,z staged in REGISTERS (issued one
// chunk ahead, written to LDS / built into lists inside the W phase). 2
// barriers per chunk (was 3), list-build off the critical path.
__global__ __launch_bounds__(512, 2) void mstep_k(
    const float* __restrict__ X, const unsigned char* __restrict__ zb,
    const float* __restrict__ wpairf,
    float* __restrict__ m2p, float* __restrict__ musp, float* __restrict__ dnp,
    int n, int nchunks)
{
  __shared__ float xls[2][CHUNK * 32];          // 64 KB
  __shared__ float wls[CHUNK * 2];              // 2 KB (single buffer)
  __shared__ unsigned char list[2][16][CHUNK];  // 8 KB
  __shared__ int lcnt[2][16];

  const int t = threadIdx.x;
  const int wv = t >> 6;      // 0..7
  const int l = t & 63;
  const int g1 = l >> 3;
  const int g2 = l & 7;
  const int G = gridDim.x;

  DECL_GRP(g00)   // cluster wv*2+0, sub 0
  DECL_GRP(g01)   // cluster wv*2+0, sub 1
  DECL_GRP(g10)   // cluster wv*2+1, sub 0
  DECL_GRP(g11)   // cluster wv*2+1, sub 1

  float wr = 0.f; int zr = 0;

  auto STAGEX = [&](int ch, int xb) {
#pragma unroll
    for (int q = 0; q < 4; ++q) {
      int gi = ch * CHUNK + wv * 32 + q * 8 + g1;
      if (gi > n - 1) gi = n - 1;
      gld_lds16(X + (size_t)gi * 32 + (g2 << 2), &xls[xb][(wv * 32 + q * 8) * 32]);
    }
  };
  auto LOADWZ = [&](int ch) {        // reg-staged w pair element + z byte
    long wi = (long)ch * (CHUNK * 2) + t;
    if (wi > 2L * n - 1) wi = 2L * n - 1;
    wr = wpairf[wi];
    if (t < CHUNK) {                 // wave-uniform predicate (waves 0..3)
      int zi = ch * CHUNK + t;
      if (zi > n - 1) zi = n - 1;
      zr = zb[zi];
    }
  };
  auto BUILD = [&](int lpb, int ch) {
    int rem = n - ch * CHUNK; if (rem > CHUNK) rem = CHUNK;
    if (t < rem) {
      int pos = atomicAdd(&lcnt[lpb][zr], 1);
      list[lpb][zr][pos] = (unsigned char)t;
    }
  };

  int ch = blockIdx.x;
  int lp = 0, xb = 0;
  if (ch < nchunks) {
    STAGEX(ch, 0);
    LOADWZ(ch);
    if (t < 32) ((int*)lcnt)[t] = 0;
    WAITVM0; WAITLGKM; BAR;          // x(ch) in LDS, regs ready, lcnt zeros visible
    wls[t] = wr; BUILD(0, ch);
    if (ch + G < nchunks) { STAGEX(ch + G, 1); LOADWZ(ch + G); }
    WAITLGKM; BAR;

    while (true) {
      const float* xbuf = xls[xb];
      const float* wb = wls;
      CLUSTER_LOOP(wv * 2 + 0, g00, g01, lp)
      CLUSTER_LOOP(wv * 2 + 1, g10, g11, lp)
      ch += G;
      WAITLGKM; BAR;                 // all reads of xls[xb]/wls/list[lp] done
      if (ch >= nchunks) break;
      WAITVM0;                       // x(ch) staged, wr/zr(ch) in regs
      wls[t] = wr;
      BUILD(lp ^ 1, ch);
      if (t < 16) lcnt[lp][t] = 0;   // pre-zero for build-after-next
      if (ch + G < nchunks) { STAGEX(ch + G, xb); LOADWZ(ch + G); }
      WAITLGKM; BAR;                 // wls/lists/zeros visible; stage in flight
      lp ^= 1; xb ^= 1;
    }
  }

  STORE_GRP(g00, wv * 4 + 0)
  STORE_GRP(g01, wv * 4 + 1)
  STORE_GRP(g10, wv * 4 + 2)
  STORE_GRP(g11, wv * 4 + 3)
}

// Parallel partial-reduction: m2p [NB][32768] via 256 blocks, musp [NB][1024]
// via 8 blocks, dnp [NB][32] via 1, pigp [PREP_GRID][32] via 1.
__global__ __launch_bounds__(256) void reduce_k(
    const float* __restrict__ m2p, const float* __restrict__ musp,
    const float* __restrict__ dnp, const float* __restrict__ pigp,
    float* __restrict__ m2r, float* __restrict__ musr,
    float* __restrict__ dnr, float* __restrict__ pigr, int NB)
{
  const int t = threadIdx.x;
  const int bid = blockIdx.x;

  if (bid < 264) {
    __shared__ float4 red[256];
    const float* in; float* outp; int rs, colbase;
    if (bid < 256) { in = m2p;  outp = m2r;  rs = 32768; colbase = bid * 32; }
    else           { in = musp; outp = musr; rs = 1024;  colbase = (bid - 256) * 32; }
    const int col = colbase + (t & 31);
    float4 a = make_float4(0.f, 0.f, 0.f, 0.f);
#pragma unroll 4
    for (int b = t >> 5; b < NB; b += 8) {
      float4 v = *(const float4*)&in[(size_t)b * rs + col * 4];
      a.x += v.x; a.y += v.y; a.z += v.z; a.w += v.w;
    }
    red[t] = a;
    __syncthreads();
    if (t < 32) {
      float4 s = red[t];
#pragma unroll
      for (int q = 1; q < 8; ++q) {
        float4 v = red[t + q * 32];
        s.x += v.x; s.y += v.y; s.z += v.z; s.w += v.w;
      }
      *(float4*)&outp[col * 4] = s;
    }
  } else {
    __shared__ float redf[256];
    const float* in; float* outp; int rows;
    if (bid == 264) { in = dnp;  outp = dnr;  rows = NB; }
    else            { in = pigp; outp = pigr; rows = PREP_GRID; }
    float a = 0.f;
    const int c = t & 31;
    for (int b = t >> 5; b < rows; b += 8) a += in[b * 32 + c];
    redf[t] = a;
    __syncthreads();
    if (t < 32) {
      float s = redf[t];
#pragma unroll
      for (int q = 1; q < 8; ++q) s += redf[t + q * 32];
      outp[c] = s;
    }
  }
}

// Final epilogue: reads only the reduced 132KB.
__global__ __launch_bounds__(256) void finalize_k(
    const float* __restrict__ pigr, const float* __restrict__ dnr,
    const float* __restrict__ musr, const float* __restrict__ m2r,
    float* __restrict__ out, int n)
{
  const int c = blockIdx.x;   // component 0..31
  const int t = threadIdx.x;
  __shared__ float mu[32];
  float safe = fmaxf(dnr[c], 1e-10f);
  if (t < 32) {
    float m = musr[c * 32 + t] / safe;
    mu[t] = m;
    out[32 + c * 32 + t] = m;                        // mus
  }
  if (c == 0 && t < 32) out[t] = pigr[t] / (float)n; // pi
  __syncthreads();
  float4 acc = *(const float4*)&m2r[c * 1024 + t * 4];
  const int d1 = t >> 3;
  const int c0 = (t * 4) & 31;
  float mud1 = mu[d1];
  float4 cov;
  cov.x = acc.x / safe - mud1 * mu[c0 + 0];
  cov.y = acc.y / safe - mud1 * mu[c0 + 1];
  cov.z = acc.z / safe - mud1 * mu[c0 + 2];
  cov.w = acc.w / safe - mud1 * mu[c0 + 3];
  *(float4*)&out[32 + 1024 + c * 1024 + t * 4] = cov;  // covs
}

extern "C" void kernel_launch(void* const* d_in, const int* in_sizes, int n_in,
                              void* d_out, int out_size, void* d_ws, size_t ws_size,
                              hipStream_t stream) {
  const float* X  = (const float*)d_in[0];
  const float* r  = (const float*)d_in[1];
  const float* ri = (const float*)d_in[2];
  float* out = (float*)d_out;
  const int n = in_sizes[0] / 32;
  const int nchunks = (n + CHUNK - 1) / CHUNK;

  // NB sized from ws: per-block partial = 32*(1024+32+1)*4 = 135,296 B.
  const size_t fixed_b = (size_t)(32768 + 1024 + 32 + 32
                                  + PREP_GRID * 32 + 2 * (size_t)n) * 4
                       + (size_t)n + 4096;
  const size_t per_nb = 32ull * (1024 + 32 + 1) * 4;
  int NB = 512;
  if (ws_size < fixed_b + (size_t)NB * per_nb) {
    size_t avail = ws_size > fixed_b ? (ws_size - fixed_b) / per_nb : 8;
    NB = (int)(avail < 8 ? 8 : avail);
    if (NB > 512) NB = 512;
  }

  // ws layout: [m2p | musp | dnp | m2r | musr | dnr | pigr | pigp | wpair | zbuf]
  float* m2p   = (float*)d_ws;                          // NB*32*1024
  float* musp  = m2p + (size_t)NB * 32 * 1024;          // NB*32*32
  float* dnp   = musp + (size_t)NB * 32 * 32;           // NB*32
  float* m2r   = dnp + (size_t)NB * 32;                 // 32768
  float* musr  = m2r + 32768;                           // 1024
  float* dnr   = musr + 1024;                           // 32
  float* pigr  = dnr + 32;                              // 32
  float* pigp  = pigr + 32;                             // PREP_GRID*32
  float* wpair = pigp + PREP_GRID * 32;                 // 2n
  unsigned char* zbuf = (unsigned char*)(wpair + 2 * (size_t)n);  // n + pad

  prep_k<<<PREP_GRID, 256, 0, stream>>>(r, ri, zbuf, wpair, pigp, n);
  mstep_k<<<NB, 512, 0, stream>>>(X, zbuf, wpair, m2p, musp, dnp, n, nchunks);
  reduce_k<<<266, 256, 0, stream>>>(m2p, musp, dnp, pigp, m2r, musr, dnr, pigr, NB);
  finalize_k<<<32, 256, 0, stream>>>(pigr, dnr, musr, m2r, out, n);
}

// Round 10
// 129.467 us; speedup vs baseline: 1.3934x; 1.3934x over previous
//
#include <hip/hip_runtime.h>

#define AS1 __attribute__((address_space(1)))
#define AS3 __attribute__((address_space(3)))
#define CHUNK 192   // 192 = 8 waves * 24 rows; LDS 57KB -> 2 blocks/CU

__device__ __forceinline__ void gld_lds16(const float* g, float* l) {
  __builtin_amdgcn_global_load_lds((const AS1 void*)g, (AS3 void*)l, 16, 0, 0);
}

#define WAITVM0  do { asm volatile("s_waitcnt vmcnt(0)" ::: "memory"); __builtin_amdgcn_sched_barrier(0); } while (0)
#define WAITLGKM do { asm volatile("s_waitcnt lgkmcnt(0)" ::: "memory"); __builtin_amdgcn_sched_barrier(0); } while (0)
#define BAR __builtin_amdgcn_s_barrier()

__global__ void zero_k(float* __restrict__ p, int n) {
  int i = blockIdx.x * blockDim.x + threadIdx.x;
  if (i < n) p[i] = 0.f;
}

// Streams r + ri once. Outputs: zb (u8 argmax), wpair (float2 gated resp),
// pig (global ri column sums via one atomic per block per column).
__global__ __launch_bounds__(256) void prep_k(
    const float* __restrict__ r, const float* __restrict__ ri,
    unsigned char* __restrict__ zb, float* __restrict__ wpairf,
    float* __restrict__ pig, int n)
{
  __shared__ float lpi[256][33];
  float acc[32];
#pragma unroll
  for (int c = 0; c < 32; ++c) acc[c] = 0.f;

  for (int i = blockIdx.x * blockDim.x + threadIdx.x; i < n;
       i += gridDim.x * blockDim.x) {
    const float4* rr = (const float4*)(r + (size_t)i * 16);
    float4 a0 = rr[0], a1 = rr[1], a2 = rr[2], a3 = rr[3];
    float best = a0.x; int z = 0;
#define CHK(v, c) if ((v) > best) { best = (v); z = (c); }
    CHK(a0.y,1) CHK(a0.z,2) CHK(a0.w,3)
    CHK(a1.x,4) CHK(a1.y,5) CHK(a1.z,6) CHK(a1.w,7)
    CHK(a2.x,8) CHK(a2.y,9) CHK(a2.z,10) CHK(a2.w,11)
    CHK(a3.x,12) CHK(a3.y,13) CHK(a3.z,14) CHK(a3.w,15)
#undef CHK
    const float4* qq = (const float4*)(ri + (size_t)i * 32);
    float4 v0 = qq[0], v1 = qq[1], v2 = qq[2], v3 = qq[3];
    float4 v4 = qq[4], v5 = qq[5], v6 = qq[6], v7 = qq[7];
    acc[0]+=v0.x; acc[1]+=v0.y; acc[2]+=v0.z; acc[3]+=v0.w;
    acc[4]+=v1.x; acc[5]+=v1.y; acc[6]+=v1.z; acc[7]+=v1.w;
    acc[8]+=v2.x; acc[9]+=v2.y; acc[10]+=v2.z; acc[11]+=v2.w;
    acc[12]+=v3.x; acc[13]+=v3.y; acc[14]+=v3.z; acc[15]+=v3.w;
    acc[16]+=v4.x; acc[17]+=v4.y; acc[18]+=v4.z; acc[19]+=v4.w;
    acc[20]+=v5.x; acc[21]+=v5.y; acc[22]+=v5.z; acc[23]+=v5.w;
    acc[24]+=v6.x; acc[25]+=v6.y; acc[26]+=v6.z; acc[27]+=v6.w;
    acc[28]+=v7.x; acc[29]+=v7.y; acc[30]+=v7.z; acc[31]+=v7.w;
    int q = z >> 1;
    float4 sel = q < 4 ? (q < 2 ? (q == 0 ? v0 : v1) : (q == 2 ? v2 : v3))
                       : (q < 6 ? (q == 4 ? v4 : v5) : (q == 6 ? v6 : v7));
    float w0 = (z & 1) ? sel.z : sel.x;
    float w1 = (z & 1) ? sel.w : sel.y;
    zb[i] = (unsigned char)z;
    *(float2*)&wpairf[(size_t)i * 2] = make_float2(w0, w1);
  }

#pragma unroll
  for (int c = 0; c < 32; ++c) lpi[threadIdx.x][c] = acc[c];
  __syncthreads();
  if (threadIdx.x < 32) {
    float s = 0.f;
    for (int q = 0; q < 256; ++q) s += lpi[q][threadIdx.x];
    atomicAdd(&pig[threadIdx.x], s);
  }
}

// ---- named-scalar accumulator groups (no arrays -> no scratch) ----
#define DECL_GRP(P) \
  float4 P##r0 = make_float4(0,0,0,0), P##r1 = make_float4(0,0,0,0), \
         P##r2 = make_float4(0,0,0,0), P##r3 = make_float4(0,0,0,0), \
         P##m  = make_float4(0,0,0,0); \
  float P##d = 0.f;

#define FMA4(ACC, S, V) \
  ACC.x += (S) * (V).x; ACC.y += (S) * (V).y; \
  ACC.z += (S) * (V).z; ACC.w += (S) * (V).w;

#define UPD_GRP(P, W, X1, X2) { float s_; \
  s_ = (W) * (X1).x; FMA4(P##r0, s_, X2); \
  s_ = (W) * (X1).y; FMA4(P##r1, s_, X2); \
  s_ = (W) * (X1).z; FMA4(P##r2, s_, X2); \
  s_ = (W) * (X1).w; FMA4(P##r3, s_, X2); \
  FMA4(P##m, W, X2); \
  P##d += (W); }

#define CLUSTER_LOOP(KK, A, B, LP) { \
  const int cnt_ = lcnt[LP][KK]; \
  const unsigned char* lk_ = &list[LP][KK][0]; \
  _Pragma("unroll 2") \
  for (int j = 0; j < cnt_; ++j) { \
    int p_ = lk_[j]; \
    float2 wp_ = *(const float2*)&wb[p_ * 2]; \
    float4 x1_ = *(const float4*)&xbuf[p_ * 32 + g1 * 4]; \
    float4 x2_ = *(const float4*)&xbuf[p_ * 32 + g2 * 4]; \
    UPD_GRP(A, wp_.x, x1_, x2_); \
    UPD_GRP(B, wp_.y, x1_, x2_); \
  } }

// Plain cached float4 stores to this block's partial slice (no global atomics:
// R3-R6 showed scattered fp32 atomicAdd = 64B uncached line traffic per touch).
#define STORE_GRP(P, COMP) { \
  float* dst_ = m2p + ((size_t)blockIdx.x * 32 + (COMP)) * 1024; \
  *(float4*)&dst_[(g1 * 4 + 0) * 32 + g2 * 4] = P##r0; \
  *(float4*)&dst_[(g1 * 4 + 1) * 32 + g2 * 4] = P##r1; \
  *(float4*)&dst_[(g1 * 4 + 2) * 32 + g2 * 4] = P##r2; \
  *(float4*)&dst_[(g1 * 4 + 3) * 32 + g2 * 4] = P##r3; \
  if (g1 == 0) \
    *(float4*)&musp[((size_t)blockIdx.x * 32 + (COMP)) * 32 + g2 * 4] = P##m; \
  if (l == 0) dnp[blockIdx.x * 32 + (COMP)] = P##d; }

// X double-buffered via global_load_lds; w,z reg-staged one chunk ahead.
// CHUNK=192 -> LDS 57KB -> 2 blocks/CU actually resident (R3-R9 ran at
// 1 block/CU: 77KB+ LDS didn't co-fit -> Occupancy ~19%, wall = 2x).
__global__ __launch_bounds__(512, 2) void mstep_k(
    const float* __restrict__ X, const unsigned char* __restrict__ zb,
    const float* __restrict__ wpairf,
    float* __restrict__ m2p, float* __restrict__ musp, float* __restrict__ dnp,
    int n, int nchunks)
{
  __shared__ float xls[2][CHUNK * 32];          // 48 KB
  __shared__ float wls[CHUNK * 2];              // 1.5 KB
  __shared__ unsigned char list[2][16][CHUNK];  // 6 KB
  __shared__ int lcnt[2][16];

  const int t = threadIdx.x;
  const int wv = t >> 6;      // 0..7
  const int l = t & 63;
  const int g1 = l >> 3;
  const int g2 = l & 7;
  const int G = gridDim.x;

  DECL_GRP(g00)   // cluster wv*2+0, sub 0
  DECL_GRP(g01)   // cluster wv*2+0, sub 1
  DECL_GRP(g10)   // cluster wv*2+1, sub 0
  DECL_GRP(g11)   // cluster wv*2+1, sub 1

  float wr = 0.f; int zr = 0;

  auto STAGEX = [&](int ch, int xb) {
#pragma unroll
    for (int q = 0; q < 3; ++q) {     // 24 rows/wave, 8 rows/instr
      int gi = ch * CHUNK + wv * 24 + q * 8 + g1;
      if (gi > n - 1) gi = n - 1;
      gld_lds16(X + (size_t)gi * 32 + (g2 << 2), &xls[xb][(wv * 24 + q * 8) * 32]);
    }
  };
  auto LOADWZ = [&](int ch) {         // reg-staged w element + z byte
    long wi = (long)ch * (CHUNK * 2) + t;
    if (wi > 2L * n - 1) wi = 2L * n - 1;
    wr = wpairf[wi];
    if (t < CHUNK) {                  // 192 = 3 waves, wave-uniform
      int zi = ch * CHUNK + t;
      if (zi > n - 1) zi = n - 1;
      zr = zb[zi];
    }
  };
  auto BUILD = [&](int lpb, int ch) {
    int rem = n - ch * CHUNK; if (rem > CHUNK) rem = CHUNK;
    if (t < rem) {
      int pos = atomicAdd(&lcnt[lpb][zr], 1);
      list[lpb][zr][pos] = (unsigned char)t;
    }
  };

  int ch = blockIdx.x;
  int lp = 0, xb = 0;
  if (ch < nchunks) {
    STAGEX(ch, 0);
    LOADWZ(ch);
    if (t < 32) ((int*)lcnt)[t] = 0;
    WAITVM0; WAITLGKM; BAR;           // x(ch) in LDS, regs ready, zeros visible
    if (t < CHUNK * 2) wls[t] = wr;
    BUILD(0, ch);
    if (ch + G < nchunks) { STAGEX(ch + G, 1); LOADWZ(ch + G); }
    WAITLGKM; BAR;

    while (true) {
      const float* xbuf = xls[xb];
      const float* wb = wls;
      CLUSTER_LOOP(wv * 2 + 0, g00, g01, lp)
      CLUSTER_LOOP(wv * 2 + 1, g10, g11, lp)
      ch += G;
      WAITLGKM; BAR;                  // all reads of xls[xb]/wls/list[lp] done
      if (ch >= nchunks) break;
      WAITVM0;                        // x(ch) staged, wr/zr(ch) in regs
      if (t < CHUNK * 2) wls[t] = wr;
      BUILD(lp ^ 1, ch);
      if (t < 16) lcnt[lp][t] = 0;    // pre-zero for build-after-next
      if (ch + G < nchunks) { STAGEX(ch + G, xb); LOADWZ(ch + G); }
      WAITLGKM; BAR;                  // wls/lists/zeros visible; stage in flight
      lp ^= 1; xb ^= 1;
    }
  }

  STORE_GRP(g00, wv * 4 + 0)
  STORE_GRP(g01, wv * 4 + 1)
  STORE_GRP(g10, wv * 4 + 2)
  STORE_GRP(g11, wv * 4 + 3)
}

// Parallel partial-reduction: m2p [NB][32768] via 256 blocks, musp [NB][1024]
// via 8 blocks, dnp [NB][32] via 1 block.
__global__ __launch_bounds__(256) void reduce_k(
    const float* __restrict__ m2p, const float* __restrict__ musp,
    const float* __restrict__ dnp,
    float* __restrict__ m2r, float* __restrict__ musr, float* __restrict__ dnr,
    int NB)
{
  const int t = threadIdx.x;
  const int bid = blockIdx.x;

  if (bid < 264) {
    __shared__ float4 red[256];
    const float* in; float* outp; int rs, colbase;
    if (bid < 256) { in = m2p;  outp = m2r;  rs = 32768; colbase = bid * 32; }
    else           { in = musp; outp = musr; rs = 1024;  colbase = (bid - 256) * 32; }
    const int col = colbase + (t & 31);
    float4 a = make_float4(0.f, 0.f, 0.f, 0.f);
#pragma unroll 4
    for (int b = t >> 5; b < NB; b += 8) {
      float4 v = *(const float4*)&in[(size_t)b * rs + col * 4];
      a.x += v.x; a.y += v.y; a.z += v.z; a.w += v.w;
    }
    red[t] = a;
    __syncthreads();
    if (t < 32) {
      float4 s = red[t];
#pragma unroll
      for (int q = 1; q < 8; ++q) {
        float4 v = red[t + q * 32];
        s.x += v.x; s.y += v.y; s.z += v.z; s.w += v.w;
      }
      *(float4*)&outp[col * 4] = s;
    }
  } else {
    __shared__ float redf[256];
    float a = 0.f;
    const int c = t & 31;
#pragma unroll 4
    for (int b = t >> 5; b < NB; b += 8) a += dnp[b * 32 + c];
    redf[t] = a;
    __syncthreads();
    if (t < 32) {
      float s = redf[t];
#pragma unroll
      for (int q = 1; q < 8; ++q) s += redf[t + q * 32];
      dnr[c] = s;
    }
  }
}

// Final epilogue: reads only the reduced 132KB.
__global__ __launch_bounds__(256) void finalize_k(
    const float* __restrict__ pig, const float* __restrict__ dnr,
    const float* __restrict__ musr, const float* __restrict__ m2r,
    float* __restrict__ out, int n)
{
  const int c = blockIdx.x;   // component 0..31
  const int t = threadIdx.x;
  __shared__ float mu[32];
  float safe = fmaxf(dnr[c], 1e-10f);
  if (t < 32) {
    float m = musr[c * 32 + t] / safe;
    mu[t] = m;
    out[32 + c * 32 + t] = m;                       // mus
  }
  if (c == 0 && t < 32) out[t] = pig[t] / (float)n; // pi
  __syncthreads();
  float4 acc = *(const float4*)&m2r[c * 1024 + t * 4];
  const int d1 = t >> 3;
  const int c0 = (t * 4) & 31;
  float mud1 = mu[d1];
  float4 cov;
  cov.x = acc.x / safe - mud1 * mu[c0 + 0];
  cov.y = acc.y / safe - mud1 * mu[c0 + 1];
  cov.z = acc.z / safe - mud1 * mu[c0 + 2];
  cov.w = acc.w / safe - mud1 * mu[c0 + 3];
  *(float4*)&out[32 + 1024 + c * 1024 + t * 4] = cov;  // covs
}

extern "C" void kernel_launch(void* const* d_in, const int* in_sizes, int n_in,
                              void* d_out, int out_size, void* d_ws, size_t ws_size,
                              hipStream_t stream) {
  const float* X  = (const float*)d_in[0];
  const float* r  = (const float*)d_in[1];
  const float* ri = (const float*)d_in[2];
  float* out = (float*)d_out;
  const int n = in_sizes[0] / 32;
  const int nchunks = (n + CHUNK - 1) / CHUNK;

  // NB sized from ws: per-block partial = 32*(1024+32+1)*4 = 135,296 B.
  const size_t fixed_b = (size_t)(32768 + 1024 + 32 + 32 + 2 * (size_t)n) * 4
                       + (size_t)n + 4096;
  const size_t per_nb = 32ull * (1024 + 32 + 1) * 4;
  int NB = 512;
  if (ws_size < fixed_b + (size_t)NB * per_nb) {
    size_t avail = ws_size > fixed_b ? (ws_size - fixed_b) / per_nb : 8;
    NB = (int)(avail < 8 ? 8 : avail);
    if (NB > 512) NB = 512;
  }

  // ws layout: [m2p | musp | dnp | m2r | musr | dnr | pig | wpair | zbuf]
  float* m2p   = (float*)d_ws;                          // NB*32*1024
  float* musp  = m2p + (size_t)NB * 32 * 1024;          // NB*32*32
  float* dnp   = musp + (size_t)NB * 32 * 32;           // NB*32
  float* m2r   = dnp + (size_t)NB * 32;                 // 32768
  float* musr  = m2r + 32768;                           // 1024
  float* dnr   = musr + 1024;                           // 32
  float* pig   = dnr + 32;                              // 32
  float* wpair = pig + 32;                              // 2n
  unsigned char* zbuf = (unsigned char*)(wpair + 2 * (size_t)n);  // n + pad

  zero_k<<<1, 32, 0, stream>>>(pig, 32);
  prep_k<<<1024, 256, 0, stream>>>(r, ri, zbuf, wpair, pig, n);
  mstep_k<<<NB, 512, 0, stream>>>(X, zbuf, wpair, m2p, musp, dnp, n, nchunks);
  reduce_k<<<265, 256, 0, stream>>>(m2p, musp, dnp, m2r, musr, dnr, NB);
  finalize_k<<<32, 256, 0, stream>>>(pig, dnr, musr, m2r, out, n);
}